// Round 7
// baseline (1336.272 us; speedup 1.0000x reference)
//
#include <hip/hip_runtime.h>
#include <hip/hip_bf16.h>
#include <math.h>

// Problem constants (fixed by the reference)
#define NN 50000
#define EE 400000
#define TT 4
#define DIN 64
#define DD 128
#define BB 64
#define STEPS 8
#define KTOT2 640   // 512 (g part: 4 types x 128) + 128 (h part) -- composed-gate GEMM
#define NGATES 512  // [r_sum, z_sum, i_n, h_n]
#define NBIN (4 * NN)             // (dst, etype) bins
#define NBLK ((NBIN + 255) / 256) // 782 scan blocks
#define MT64 ((NN + 63) / 64)     // 782 fused blocks

typedef __attribute__((ext_vector_type(8))) short bf16x8;
typedef __attribute__((ext_vector_type(4))) float f32x4;

__device__ inline float bf2f(__hip_bfloat16 x) { return __bfloat162float(x); }

// ---------------------------------------------------------------- init (zero-pad 64->128)
__global__ void k_init_h(const float* __restrict__ feat, float* __restrict__ h1,
                         __hip_bfloat16* __restrict__ hb) {
    int idx = blockIdx.x * blockDim.x + threadIdx.x;
    if (idx >= NN * DD) return;
    int v = idx >> 7, d = idx & 127;
    float val = (d < DIN) ? feat[v * DIN + d] : 0.0f;
    h1[idx] = val;
    hb[idx] = __float2bfloat16(val);
}

__global__ void k_zero_i32(int* __restrict__ p, int n) {
    int idx = blockIdx.x * blockDim.x + threadIdx.x;
    if (idx < n) p[idx] = 0;
}
__global__ void k_zero_f32(float* __restrict__ p, int n) {
    int idx = blockIdx.x * blockDim.x + threadIdx.x;
    if (idx < n) p[idx] = 0.0f;
}

// ---------------------------------------------------------------- CSR build by (dst,type)
__global__ void k_hist(const int* __restrict__ dst, const int* __restrict__ etype,
                       int* __restrict__ deg2) {
    int e = blockIdx.x * blockDim.x + threadIdx.x;
    if (e < EE) atomicAdd(&deg2[dst[e] * 4 + etype[e]], 1);
}

__global__ __launch_bounds__(256) void k_scan_bsum(const int* __restrict__ deg2,
                                                   int* __restrict__ bsum) {
    __shared__ int red[256];
    int tid = threadIdx.x;
    int i = blockIdx.x * 256 + tid;
    int v = (i < NBIN) ? deg2[i] : 0;
    red[tid] = v;
    __syncthreads();
#pragma unroll
    for (int s = 128; s > 0; s >>= 1) {
        if (tid < s) red[tid] += red[tid + s];
        __syncthreads();
    }
    if (tid == 0) bsum[blockIdx.x] = red[0];
}

__global__ __launch_bounds__(1024) void k_scan_boff(const int* __restrict__ bsum,
                                                    int* __restrict__ boff) {
    __shared__ int s[1024];
    int tid = threadIdx.x;
    int v = (tid < NBLK) ? bsum[tid] : 0;
    s[tid] = v;
    __syncthreads();
    for (int d = 1; d < 1024; d <<= 1) {
        int t = (tid >= d) ? s[tid - d] : 0;
        __syncthreads();
        s[tid] += t;
        __syncthreads();
    }
    if (tid < NBLK) boff[tid] = s[tid] - v;  // exclusive
}

__global__ __launch_bounds__(256) void k_scan_final(const int* __restrict__ deg2,
                                                    const int* __restrict__ boff,
                                                    int* __restrict__ off2,
                                                    int* __restrict__ cursor) {
    __shared__ int s[256];
    int tid = threadIdx.x;
    int i = blockIdx.x * 256 + tid;
    int v = (i < NBIN) ? deg2[i] : 0;
    s[tid] = v;
    __syncthreads();
#pragma unroll
    for (int d = 1; d < 256; d <<= 1) {
        int t = (tid >= d) ? s[tid - d] : 0;
        __syncthreads();
        s[tid] += t;
        __syncthreads();
    }
    int excl = boff[blockIdx.x] + s[tid] - v;
    if (i < NBIN) {
        off2[i] = excl;
        cursor[i] = excl;
        if (i == NBIN - 1) off2[NBIN] = excl + v;  // == EE
    }
}

__global__ void k_fill(const int* __restrict__ dst, const int* __restrict__ src,
                       const int* __restrict__ etype, int* __restrict__ cursor,
                       int* __restrict__ csr_src) {
    int e = blockIdx.x * blockDim.x + threadIdx.x;
    if (e < EE) {
        int pos = atomicAdd(&cursor[dst[e] * 4 + etype[e]], 1);
        csr_src[pos] = src[e];
    }
}

// ---------------------------------------------------------------- weight prep (once/call)
// W2b[512 n][640 k] bf16: k<512 -> composed Sum_e Wm[t][kd][e]*wih[e][n] for n<384
// (0 for h_n cols), t=k>>7, kd=k&127; k>=512 -> w_hh structured (0 for i_n cols).
// Cmat[4][384] fp32: C[t][n] = Sum_e b_msg[t][e]*wih[e][n]  (count contribution).
// bias512: 0..255 bih+bhh (r,z); 256..383 bih (i_n); 384..511 bhh[256..384] (h_n).
__global__ void k_prep3(const float* __restrict__ Wm, const float* __restrict__ bm,
                        const float* __restrict__ wih, const float* __restrict__ whh,
                        const float* __restrict__ bih, const float* __restrict__ bhh,
                        __hip_bfloat16* __restrict__ W2b, float* __restrict__ Cmat,
                        float* __restrict__ bias512) {
    int idx = blockIdx.x * blockDim.x + threadIdx.x;
    if (idx < 512 * KTOT2) {
        int n = idx / KTOT2, k = idx % KTOT2;
        float v = 0.0f;
        if (k < 512) {
            if (n < 384) {
                int t = k >> 7, kd = k & 127;
                const float* wr = Wm + (t << 14) + (kd << 7);
                float s = 0.0f;
#pragma unroll 4
                for (int e = 0; e < 128; ++e) s += wr[e] * wih[e * 384 + n];
                v = s;
            }
        } else {
            int kd = k - 512;
            if (n < 256) v = whh[kd * 384 + n];
            else if (n >= 384) v = whh[kd * 384 + n - 128];
        }
        W2b[idx] = __float2bfloat16(v);
        return;
    }
    int j = idx - 512 * KTOT2;
    if (j < 4 * 384) {
        int t = j / 384, n = j % 384;
        const float* br = bm + t * 128;
        float s = 0.0f;
#pragma unroll 4
        for (int e = 0; e < 128; ++e) s += br[e] * wih[e * 384 + n];
        Cmat[j] = s;
        return;
    }
    int b = j - 4 * 384;
    if (b < NGATES) {
        float v;
        if (b < 256) v = bih[b] + bhh[b];
        else if (b < 384) v = bih[b];
        else v = bhh[b - 128];
        bias512[b] = v;
    }
}

// ---------------------------------------------------------------- FUSED agg + step kernel
// Per block (64 dst nodes): gather-phase builds A-tile [64][512 g | 128 h] bf16 in LDS
// (fp32 register accumulate, swizzled ds_write) -- the 'g' intermediate never touches
// HBM. One barrier, then composed GEMM gates[64x512] = A @ W2b^T with B-fragments
// loaded per-wave DIRECTLY from global (W2b is L2-resident; imm-offset folded) ->
// zero barriers in the K-loop. Swizzle: 16B part index p -> p ^ f(row),
// f(r) = (r^(r>>2))&3, coherent between ds_write side and af ds_read side.
// Counts contribution (cnt_t * b_msg_t @ w_ih) applied in epilogue via Cmat.
__global__ __launch_bounds__(512, 4) void k_fused(const __hip_bfloat16* __restrict__ hbi,
                                                  const int* __restrict__ off2,
                                                  const int* __restrict__ csr_src,
                                                  const __hip_bfloat16* __restrict__ W2b,
                                                  const float* __restrict__ Cmat,
                                                  const float* __restrict__ bias512,
                                                  __hip_bfloat16* __restrict__ hbo) {
    __shared__ __align__(16) short A[64 * KTOT2];  // 81,920 B exactly -> 2 blocks/CU
    const int tid = threadIdx.x;
    const int lane = tid & 63;
    const int wave = tid >> 6;
    const int row0 = blockIdx.x * 64;
    const int quad = lane >> 4;
    const int m16 = lane & 15;
    const int fm = (m16 ^ (m16 >> 2)) & 3;   // read-side row-swizzle key (row = rt*16+m16)
    const int koff = (quad ^ fm) << 3;       // swizzled 16B-part offset (shorts)
    const int brb = wave * 16 + m16;

    // ---- stage h rows into A cols 512..639 (register round-trip, swizzled write) ----
#pragma unroll
    for (int rep = 0; rep < 2; ++rep) {
        int slot = tid + rep * 512;       // 1024 slots = 64 rows x 16 parts
        int row = slot >> 4;
        int p = slot & 15;
        int grow = row0 + row;
        if (grow >= NN) grow = NN - 1;
        bf16x8 v = *(const bf16x8*)(hbi + (size_t)grow * DD + p * 8);
        int fr = (row ^ (row >> 2)) & 3;
        *(bf16x8*)&A[row * KTOT2 + 512 + ((p ^ fr) << 3)] = v;
    }

    // ---- gather phase: wave w owns rows w*8 .. w*8+7; lane owns dims (2*lane, 2*lane+1)
    const __hip_bfloat162* hb2 = (const __hip_bfloat162*)hbi;
    for (int i = 0; i < 8; ++i) {
        const int lr = wave * 8 + i;
        const int v = row0 + lr;
        const int fr = (lr ^ (lr >> 2)) & 3;
        float ax[4], ay[4];
#pragma unroll
        for (int t = 0; t < 4; ++t) { ax[t] = 0.0f; ay[t] = 0.0f; }
        if (v < NN) {
            int b[5];
#pragma unroll
            for (int j = 0; j < 5; ++j) b[j] = off2[4 * v + j];
#pragma unroll
            for (int t = 0; t < 4; ++t) {
                int p = b[t], e = b[t + 1];
                float sx = 0.0f, sy = 0.0f;
                for (; p + 1 < e; p += 2) {
                    int s0 = csr_src[p];
                    int s1 = csr_src[p + 1];
                    __hip_bfloat162 v0 = hb2[(size_t)s0 * 64 + lane];
                    __hip_bfloat162 v1 = hb2[(size_t)s1 * 64 + lane];
                    sx += bf2f(v0.x) + bf2f(v1.x);
                    sy += bf2f(v0.y) + bf2f(v1.y);
                }
                if (p < e) {
                    int s0 = csr_src[p];
                    __hip_bfloat162 v0 = hb2[(size_t)s0 * 64 + lane];
                    sx += bf2f(v0.x);
                    sy += bf2f(v0.y);
                }
                ax[t] = sx; ay[t] = sy;
            }
        }
#pragma unroll
        for (int t = 0; t < 4; ++t) {
            __hip_bfloat162 o;
            o.x = __float2bfloat16(ax[t]);
            o.y = __float2bfloat16(ay[t]);
            int pp = (t << 4) + (lane >> 2);         // logical 16B part (0..63)
            int pps = pp ^ fr;                        // fr<=3: XORs low2 only (group-safe)
            *(__hip_bfloat162*)&A[lr * KTOT2 + (pps << 3) + 2 * (lane & 3)] = o;
        }
    }
    __syncthreads();  // A-tile complete

    // ---- GEMM: 20 chunks of K=32, no barriers; B direct from global (L2-hot) ----
    f32x4 acc[4][4];  // [row-tile][gate: r,z,in,hn]
#pragma unroll
    for (int rt = 0; rt < 4; ++rt)
#pragma unroll
        for (int c = 0; c < 4; ++c) acc[rt][c] = (f32x4){0.f, 0.f, 0.f, 0.f};

    const __hip_bfloat16* pb0 = W2b + (size_t)brb * KTOT2 + quad * 8;
    const __hip_bfloat16* pb1 = W2b + (size_t)(128 + brb) * KTOT2 + quad * 8;
    const __hip_bfloat16* pb2g = W2b + (size_t)(256 + brb) * KTOT2 + quad * 8;
    const __hip_bfloat16* pb2h = W2b + (size_t)(384 + brb) * KTOT2 + quad * 8;

#pragma unroll 4
    for (int ki = 0; ki < 16; ++ki) {  // g chunks -> acc[.][0,1,2]
        bf16x8 b0 = *(const bf16x8*)(pb0 + ki * 32);
        bf16x8 b1 = *(const bf16x8*)(pb1 + ki * 32);
        bf16x8 b2 = *(const bf16x8*)(pb2g + ki * 32);
        bf16x8 af[4];
#pragma unroll
        for (int rt = 0; rt < 4; ++rt)
            af[rt] = *(const bf16x8*)&A[(rt * 16 + m16) * KTOT2 + ki * 32 + koff];
#pragma unroll
        for (int rt = 0; rt < 4; ++rt)
            acc[rt][0] = __builtin_amdgcn_mfma_f32_16x16x32_bf16(af[rt], b0, acc[rt][0], 0, 0, 0);
#pragma unroll
        for (int rt = 0; rt < 4; ++rt)
            acc[rt][1] = __builtin_amdgcn_mfma_f32_16x16x32_bf16(af[rt], b1, acc[rt][1], 0, 0, 0);
#pragma unroll
        for (int rt = 0; rt < 4; ++rt)
            acc[rt][2] = __builtin_amdgcn_mfma_f32_16x16x32_bf16(af[rt], b2, acc[rt][2], 0, 0, 0);
    }
#pragma unroll
    for (int ki = 16; ki < 20; ++ki) {  // h chunks -> acc[.][0,1,3]
        bf16x8 b0 = *(const bf16x8*)(pb0 + ki * 32);
        bf16x8 b1 = *(const bf16x8*)(pb1 + ki * 32);
        bf16x8 b2 = *(const bf16x8*)(pb2h + ki * 32);
        bf16x8 af[4];
#pragma unroll
        for (int rt = 0; rt < 4; ++rt)
            af[rt] = *(const bf16x8*)&A[(rt * 16 + m16) * KTOT2 + ki * 32 + koff];
#pragma unroll
        for (int rt = 0; rt < 4; ++rt)
            acc[rt][0] = __builtin_amdgcn_mfma_f32_16x16x32_bf16(af[rt], b0, acc[rt][0], 0, 0, 0);
#pragma unroll
        for (int rt = 0; rt < 4; ++rt)
            acc[rt][1] = __builtin_amdgcn_mfma_f32_16x16x32_bf16(af[rt], b1, acc[rt][1], 0, 0, 0);
#pragma unroll
        for (int rt = 0; rt < 4; ++rt)
            acc[rt][3] = __builtin_amdgcn_mfma_f32_16x16x32_bf16(af[rt], b2, acc[rt][3], 0, 0, 0);
    }
    __syncthreads();  // all A reads done before reuse as Ht

    // ---- epilogue: counts + GRU (wave-local d-slice) -> LDS -> full-line store ----
    short* Ht = A;  // 64 x 128 bf16 at stride 132 (bank-staggered), reuses A
    {
        const int d = brb;
        const float brs = bias512[d];
        const float bzs = bias512[128 + d];
        const float bin_ = bias512[256 + d];
        const float bhn = bias512[384 + d];
        const float c0r = Cmat[d],       c1r = Cmat[384 + d],       c2r = Cmat[768 + d],       c3r = Cmat[1152 + d];
        const float c0z = Cmat[128 + d], c1z = Cmat[512 + d],       c2z = Cmat[896 + d],       c3z = Cmat[1280 + d];
        const float c0n = Cmat[256 + d], c1n = Cmat[640 + d],       c2n = Cmat[1024 + d],      c3n = Cmat[1408 + d];
#pragma unroll
        for (int rt = 0; rt < 4; ++rt) {
#pragma unroll
            for (int j = 0; j < 4; ++j) {
                const int rowl = rt * 16 + quad * 4 + j;
                const int grow = row0 + rowl;
                if (grow >= NN) continue;
                const int* o2 = off2 + 4 * grow;
                const float cnt0 = (float)(o2[1] - o2[0]);
                const float cnt1 = (float)(o2[2] - o2[1]);
                const float cnt2 = (float)(o2[3] - o2[2]);
                const float cnt3 = (float)(o2[4] - o2[3]);
                const float rs = acc[rt][0][j] + brs + cnt0 * c0r + cnt1 * c1r + cnt2 * c2r + cnt3 * c3r;
                const float zs = acc[rt][1][j] + bzs + cnt0 * c0z + cnt1 * c1z + cnt2 * c2z + cnt3 * c3z;
                const float inn = acc[rt][2][j] + bin_ + cnt0 * c0n + cnt1 * c1n + cnt2 * c2n + cnt3 * c3n;
                const float hnn = acc[rt][3][j] + bhn;
                const float rr = 1.0f / (1.0f + __expf(-rs));
                const float zz = 1.0f / (1.0f + __expf(-zs));
                const float ng = tanhf(inn + rr * hnn);
                const float hv = bf2f(hbi[(size_t)grow * DD + d]);
                const float o = (1.0f - zz) * ng + zz * hv;
                __hip_bfloat16 ob = __float2bfloat16(o);
                Ht[rowl * 132 + d] = *(short*)&ob;
            }
        }
    }
    __syncthreads();
    {
        // 512 threads x 32 B contiguous -> fully-coalesced full-line stores
        const int row = tid >> 3;
        const int col = (tid & 7) * 16;
        if (row0 + row < NN) {
            bf16x8 v0 = *(const bf16x8*)&Ht[row * 132 + col];
            bf16x8 v1 = *(const bf16x8*)&Ht[row * 132 + col + 8];
            __hip_bfloat16* dstp = hbo + (size_t)(row0 + row) * DD + col;
            *(bf16x8*)dstp = v0;
            *(bf16x8*)(dstp + 8) = v1;
        }
    }
}

// ---------------------------------------------------------------- readout (n2g is sorted)
__global__ __launch_bounds__(128) void k_readout(const __hip_bfloat16* __restrict__ h,
                                                 const float* __restrict__ h1,
                                                 const int* __restrict__ n2g,
                                                 float* __restrict__ feats) {
    const int CHN = 64;
    int d = threadIdx.x;
    int v0 = blockIdx.x * CHN;
    if (v0 >= NN) return;
    int v1 = v0 + CHN;
    if (v1 > NN) v1 = NN;
    float sum = 0.0f;
    int cur = n2g[v0];
    for (int v = v0; v < v1; ++v) {
        int gph = n2g[v];
        if (gph != cur) {
            atomicAdd(&feats[cur * DD + d], sum);
            sum = 0.0f;
            cur = gph;
        }
        sum += bf2f(h[(size_t)v * DD + d]) + h1[(size_t)v * DD + d];
    }
    atomicAdd(&feats[cur * DD + d], sum);
}

// ---------------------------------------------------------------- classifier
__global__ void k_cls(const float* __restrict__ feats, const float* __restrict__ Wc,
                      const float* __restrict__ bc, float* __restrict__ out) {
    int t = threadIdx.x;
    if (t >= BB * 2) return;
    int b = t >> 1, c = t & 1;
    float s = bc[c];
    for (int d = 0; d < DD; ++d) s += feats[b * DD + d] * Wc[d * 2 + c];
    out[t] = s;
}

// ================================================================ launcher
extern "C" void kernel_launch(void* const* d_in, const int* in_sizes, int n_in, void* d_out,
                              int out_size, void* d_ws, size_t ws_size, hipStream_t stream) {
    const float* features = (const float*)d_in[0];
    const int* src = (const int*)d_in[1];
    const int* dst = (const int*)d_in[2];
    const int* etype = (const int*)d_in[3];
    const int* n2g = (const int*)d_in[4];
    const float* W_msg = (const float*)d_in[5];
    const float* b_msg = (const float*)d_in[6];
    const float* w_ih = (const float*)d_in[7];
    const float* b_ih = (const float*)d_in[8];
    const float* w_hh = (const float*)d_in[9];
    const float* b_hh = (const float*)d_in[10];
    const float* W_cls = (const float*)d_in[11];
    const float* b_cls = (const float*)d_in[12];
    float* out = (float*)d_out;

    char* ws = (char*)d_ws;
    size_t o = 0;
    auto alloc = [&](size_t bytes) {
        o = (o + 255) & ~(size_t)255;
        void* p = ws + o;
        o += bytes;
        return p;
    };
    int* deg2 = (int*)alloc(sizeof(int) * NBIN);
    int* off2 = (int*)alloc(sizeof(int) * (NBIN + 1));
    int* cursor = (int*)alloc(sizeof(int) * NBIN);
    int* bsum = (int*)alloc(sizeof(int) * NBLK);
    int* boff = (int*)alloc(sizeof(int) * NBLK);
    int* csr_src = (int*)alloc(sizeof(int) * EE);
    __hip_bfloat16* W2b = (__hip_bfloat16*)alloc(sizeof(__hip_bfloat16) * 512 * KTOT2);
    float* Cmat = (float*)alloc(sizeof(float) * 4 * 384);
    float* bias512 = (float*)alloc(sizeof(float) * NGATES);
    float* hini = (float*)alloc(sizeof(float) * (size_t)NN * DD);
    __hip_bfloat16* hbfA = (__hip_bfloat16*)alloc(sizeof(__hip_bfloat16) * (size_t)NN * DD);
    __hip_bfloat16* hbfB = (__hip_bfloat16*)alloc(sizeof(__hip_bfloat16) * (size_t)NN * DD);
    float* feats = (float*)alloc(sizeof(float) * BB * DD);

    // setup
    k_init_h<<<(NN * DD + 255) / 256, 256, 0, stream>>>(features, hini, hbfA);
    k_zero_i32<<<(NBIN + 255) / 256, 256, 0, stream>>>(deg2, NBIN);
    k_zero_f32<<<(BB * DD + 255) / 256, 256, 0, stream>>>(feats, BB * DD);
    k_hist<<<(EE + 255) / 256, 256, 0, stream>>>(dst, etype, deg2);
    k_scan_bsum<<<NBLK, 256, 0, stream>>>(deg2, bsum);
    k_scan_boff<<<1, 1024, 0, stream>>>(bsum, boff);
    k_scan_final<<<NBLK, 256, 0, stream>>>(deg2, boff, off2, cursor);
    k_fill<<<(EE + 255) / 256, 256, 0, stream>>>(dst, src, etype, cursor, csr_src);
    {
        int prep_n = 512 * KTOT2 + 4 * 384 + NGATES;
        k_prep3<<<(prep_n + 255) / 256, 256, 0, stream>>>(W_msg, b_msg, w_ih, w_hh, b_ih,
                                                          b_hh, W2b, Cmat, bias512);
    }

    __hip_bfloat16* hbc = hbfA;
    __hip_bfloat16* hbx = hbfB;
    for (int s = 0; s < STEPS; ++s) {
        k_fused<<<MT64, 512, 0, stream>>>(hbc, off2, csr_src, W2b, Cmat, bias512, hbx);
        __hip_bfloat16* tb = hbc; hbc = hbx; hbx = tb;
    }
    k_readout<<<(NN + 63) / 64, 128, 0, stream>>>(hbc, hini, n2g, feats);
    k_cls<<<1, 128, 0, stream>>>(feats, W_cls, b_cls, out);
}

// Round 9
// 880.666 us; speedup vs baseline: 1.5173x; 1.5173x over previous
//
#include <hip/hip_runtime.h>
#include <hip/hip_bf16.h>
#include <math.h>

// Problem constants (fixed by the reference)
#define NN 50000
#define EE 400000
#define TT 4
#define DIN 64
#define DD 128
#define BB 64
#define STEPS 8
#define KAGG 544    // 512 (T*D) + 4 (per-type counts for b_msg) + 28 pad -> 17*32
#define KTOT 672    // 544 (g part) + 128 (h part) for the composed-gate GEMM
#define NGATES 512  // [r_sum, z_sum, i_n, h_n]
#define NBIN (4 * NN)             // (dst, etype) bins
#define NBLK ((NBIN + 255) / 256) // 782 scan blocks
#define MT64 ((NN + 63) / 64)     // 782 step blocks

typedef __attribute__((ext_vector_type(8))) short bf16x8;
typedef __attribute__((ext_vector_type(4))) float f32x4;
typedef __attribute__((address_space(3))) void lds_void;
typedef __attribute__((address_space(1))) void glob_void;

__device__ inline float bf2f(__hip_bfloat16 x) { return __bfloat162float(x); }

// exact bf16(bit pattern in short) -> f32, value-based (vector elements have no address)
__device__ inline float s2f(short s) {
    unsigned int u = ((unsigned int)(unsigned short)s) << 16;
    float f;
    __builtin_memcpy(&f, &u, 4);
    return f;
}

// ---------------------------------------------------------------- init (zero-pad 64->128)
__global__ void k_init_h(const float* __restrict__ feat, float* __restrict__ h1,
                         __hip_bfloat16* __restrict__ hb) {
    int idx = blockIdx.x * blockDim.x + threadIdx.x;
    if (idx >= NN * DD) return;
    int v = idx >> 7, d = idx & 127;
    float val = (d < DIN) ? feat[v * DIN + d] : 0.0f;
    h1[idx] = val;
    hb[idx] = __float2bfloat16(val);
}

__global__ void k_zero_i32(int* __restrict__ p, int n) {
    int idx = blockIdx.x * blockDim.x + threadIdx.x;
    if (idx < n) p[idx] = 0;
}
__global__ void k_zero_f32(float* __restrict__ p, int n) {
    int idx = blockIdx.x * blockDim.x + threadIdx.x;
    if (idx < n) p[idx] = 0.0f;
}

// ---------------------------------------------------------------- CSR build by (dst,type)
__global__ void k_hist(const int* __restrict__ dst, const int* __restrict__ etype,
                       int* __restrict__ deg2) {
    int e = blockIdx.x * blockDim.x + threadIdx.x;
    if (e < EE) atomicAdd(&deg2[dst[e] * 4 + etype[e]], 1);
}

__global__ __launch_bounds__(256) void k_scan_bsum(const int* __restrict__ deg2,
                                                   int* __restrict__ bsum) {
    __shared__ int red[256];
    int tid = threadIdx.x;
    int i = blockIdx.x * 256 + tid;
    int v = (i < NBIN) ? deg2[i] : 0;
    red[tid] = v;
    __syncthreads();
#pragma unroll
    for (int s = 128; s > 0; s >>= 1) {
        if (tid < s) red[tid] += red[tid + s];
        __syncthreads();
    }
    if (tid == 0) bsum[blockIdx.x] = red[0];
}

__global__ __launch_bounds__(1024) void k_scan_boff(const int* __restrict__ bsum,
                                                    int* __restrict__ boff) {
    __shared__ int s[1024];
    int tid = threadIdx.x;
    int v = (tid < NBLK) ? bsum[tid] : 0;
    s[tid] = v;
    __syncthreads();
    for (int d = 1; d < 1024; d <<= 1) {
        int t = (tid >= d) ? s[tid - d] : 0;
        __syncthreads();
        s[tid] += t;
        __syncthreads();
    }
    if (tid < NBLK) boff[tid] = s[tid] - v;  // exclusive
}

__global__ __launch_bounds__(256) void k_scan_final(const int* __restrict__ deg2,
                                                    const int* __restrict__ boff,
                                                    int* __restrict__ off2,
                                                    int* __restrict__ cursor) {
    __shared__ int s[256];
    int tid = threadIdx.x;
    int i = blockIdx.x * 256 + tid;
    int v = (i < NBIN) ? deg2[i] : 0;
    s[tid] = v;
    __syncthreads();
#pragma unroll
    for (int d = 1; d < 256; d <<= 1) {
        int t = (tid >= d) ? s[tid - d] : 0;
        __syncthreads();
        s[tid] += t;
        __syncthreads();
    }
    int excl = boff[blockIdx.x] + s[tid] - v;
    if (i < NBIN) {
        off2[i] = excl;
        cursor[i] = excl;
        if (i == NBIN - 1) off2[NBIN] = excl + v;  // == EE
    }
}

__global__ void k_fill(const int* __restrict__ dst, const int* __restrict__ src,
                       const int* __restrict__ etype, int* __restrict__ cursor,
                       int* __restrict__ csr_src) {
    int e = blockIdx.x * blockDim.x + threadIdx.x;
    if (e < EE) {
        int pos = atomicAdd(&cursor[dst[e] * 4 + etype[e]], 1);
        csr_src[pos] = src[e];
    }
}

// counts columns of g (cols 512..515) constant across steps; zero pad 516..543.
__global__ void k_counts(const int* __restrict__ off2, __hip_bfloat16* __restrict__ g) {
    int idx = blockIdx.x * blockDim.x + threadIdx.x;
    if (idx >= NN * 16) return;
    int v = idx >> 4, j = idx & 15;
    float x = 0.0f, y = 0.0f;
    if (j < 2) {
        int t0 = 2 * j;
        x = (float)(off2[4 * v + t0 + 1] - off2[4 * v + t0]);
        y = (float)(off2[4 * v + t0 + 2] - off2[4 * v + t0 + 1]);
    }
    __hip_bfloat162 o;
    o.x = __float2bfloat16(x);
    o.y = __float2bfloat16(y);
    ((__hip_bfloat162*)(g + (size_t)v * KAGG))[256 + j] = o;
}

// ---------------------------------------------------------------- weight prep (once/call)
// W2[512 n][672 k] bf16: k<544 -> (Wcat @ w_ih) for n<384 (0 for h_n cols);
// k>=544 -> w_hh (0 for i_n cols). Gate cols n: 0..127 r, 128..255 z, 256..383 i_n, 384..511 h_n.
__global__ void k_prep2(const float* __restrict__ Wm, const float* __restrict__ bm,
                        const float* __restrict__ wih, const float* __restrict__ whh,
                        const float* __restrict__ bih, const float* __restrict__ bhh,
                        __hip_bfloat16* __restrict__ W2, float* __restrict__ bias512) {
    int idx = blockIdx.x * blockDim.x + threadIdx.x;
    if (idx < 512 * KTOT) {
        int n = idx / KTOT, k = idx % KTOT;
        float v = 0.0f;
        if (k < 544) {
            if (n < 384 && k < 516) {
                float s = 0.0f;
                if (k < 512) {
                    int t = k >> 7, d = k & 127;
                    const float* wr = Wm + (t << 14) + (d << 7);
#pragma unroll 4
                    for (int e = 0; e < 128; ++e) s += wr[e] * wih[e * 384 + n];
                } else {
                    const float* br = bm + ((k - 512) << 7);
#pragma unroll 4
                    for (int e = 0; e < 128; ++e) s += br[e] * wih[e * 384 + n];
                }
                v = s;
            }
        } else {
            int dd = k - 544;
            if (n < 256) v = whh[dd * 384 + n];
            else if (n >= 384) v = whh[dd * 384 + n - 128];
        }
        W2[idx] = __float2bfloat16(v);
    } else {
        int b = idx - 512 * KTOT;
        if (b < NGATES) {
            float v;
            if (b < 256) v = bih[b] + bhh[b];
            else if (b < 384) v = bih[b];
            else v = bhh[b - 128];
            bias512[b] = v;
        }
    }
}

// ---------------------------------------------------------------- per-type aggregation v2
// One WAVE per node; 4x 16-lane GROUPS walk the node's 4 type-lists CONCURRENTLY
// (wave time = max walk, not sum; each load instruction covers up to 4 src rows = 1KB).
// Lane = 8 dims via bf16x8; group t writes its 256B segment g[node][t*128..t*128+127].
__global__ __launch_bounds__(256) void k_agg(const __hip_bfloat16* __restrict__ hb,
                                             const int* __restrict__ off2,
                                             const int* __restrict__ csr_src,
                                             __hip_bfloat16* __restrict__ g) {
    const int node = (blockIdx.x * blockDim.x + threadIdx.x) >> 6;
    const int lane = threadIdx.x & 63;
    if (node >= NN) return;
    const int t = lane >> 4;    // group = etype
    const int sub = lane & 15;  // 8 dims per lane
    const int p0 = off2[4 * node + t];
    const int p1 = off2[4 * node + t + 1];
    float a[8];
#pragma unroll
    for (int j = 0; j < 8; ++j) a[j] = 0.0f;
    int p = p0;
    for (; p + 1 < p1; p += 2) {
        int s0 = csr_src[p];
        int s1 = csr_src[p + 1];
        bf16x8 v0 = *(const bf16x8*)(hb + (size_t)s0 * DD + sub * 8);
        bf16x8 v1 = *(const bf16x8*)(hb + (size_t)s1 * DD + sub * 8);
#pragma unroll
        for (int j = 0; j < 8; ++j) a[j] += s2f(v0[j]) + s2f(v1[j]);
    }
    if (p < p1) {
        int s0 = csr_src[p];
        bf16x8 v0 = *(const bf16x8*)(hb + (size_t)s0 * DD + sub * 8);
#pragma unroll
        for (int j = 0; j < 8; ++j) a[j] += s2f(v0[j]);
    }
    bf16x8 o;
#pragma unroll
    for (int j = 0; j < 8; ++j) {
        __hip_bfloat16 b = __float2bfloat16(a[j]);
        o[j] = *(short*)&b;
    }
    *(bf16x8*)(g + (size_t)node * KAGG + t * 128 + sub * 8) = o;
}

// ---------------------------------------------------------------- fused step kernel (v4)
// gates[64x512] = [g(544)|h(128)] @ W2^T, composed weights, zero-blocks skipped.
// Counted-vmcnt pipeline (T3+T4): A in a 4-buffer ring staged 3 ahead; B in a
// 2-buffer ping-pong staged 1 ahead. ONE raw s_barrier per chunk; stages issue
// after the barrier; vmcnt counted, never a mid-loop full drain.
__global__ __launch_bounds__(512, 4) void k_step(const __hip_bfloat16* __restrict__ g,
                                                 const __hip_bfloat16* __restrict__ W2,
                                                 const float* __restrict__ bias512,
                                                 const __hip_bfloat16* __restrict__ hbi,
                                                 __hip_bfloat16* __restrict__ hbo) {
    __shared__ __align__(16) short As[4][64 * 32];    // 4 x 4 KB ring
    __shared__ __align__(16) short Bs[2][384 * 32];   // 2 x 24 KB ping-pong
    const int tid = threadIdx.x;
    const int lane = tid & 63;
    const int wave = tid >> 6;
    const int row0 = blockIdx.x * 64;
    const int quad = lane >> 4;
    const int m16 = lane & 15;
    const int koff = ((quad ^ ((m16 ^ (m16 >> 2)) & 3)) << 3);
    const int brb = wave * 16 + m16;

    const int arow = tid >> 2;
    const int apart = (tid & 3) ^ ((arow ^ (arow >> 2)) & 3);
    int agrow = row0 + arow;
    if (agrow >= NN) agrow = NN - 1;
    const __hip_bfloat16* gA = g + (size_t)agrow * KAGG + apart * 8;
    const __hip_bfloat16* hA = hbi + (size_t)agrow * DD + apart * 8;

    auto stage_A = [&](int kc) {
        if (wave < 4) {
            const glob_void* srcA = (kc < 17)
                                        ? (const glob_void*)(gA + kc * 32)
                                        : (const glob_void*)(hA + (kc - 17) * 32);
            __builtin_amdgcn_global_load_lds(srcA, (lds_void*)&As[kc & 3][(wave * 64) * 8],
                                             16, 0, 0);
        }
    };
    auto stage_B = [&](int kc) {
#pragma unroll
        for (int i = 0; i < 3; ++i) {
            int s = tid + i * 512;
            int br = s >> 2;
            int bpart = (s & 3) ^ ((br ^ (br >> 2)) & 3);
            int grp = br >> 7;
            int within = br & 127;
            size_t n;
            int kk;
            if (kc < 17) {
                n = (size_t)(grp * 128 + within);
                kk = kc * 32 + bpart * 8;
            } else {
                n = (size_t)((grp < 2 ? grp * 128 : 384) + within);
                kk = 544 + (kc - 17) * 32 + bpart * 8;
            }
            __builtin_amdgcn_global_load_lds((const glob_void*)(W2 + n * KTOT + kk),
                                             (lds_void*)&Bs[kc & 1][(wave * 64 + i * 512) * 8],
                                             16, 0, 0);
        }
    };

    f32x4 acc[4][4];
#pragma unroll
    for (int rt = 0; rt < 4; ++rt)
#pragma unroll
        for (int c = 0; c < 4; ++c) acc[rt][c] = (f32x4){0.f, 0.f, 0.f, 0.f};

    stage_B(0);
    stage_A(0);
    stage_A(1);
    stage_A(2);

    for (int ki = 0; ki < 21; ++ki) {
        if (wave < 4) {
            if (ki == 0)
                asm volatile("s_waitcnt vmcnt(2)" ::: "memory");
            else if (ki <= 18)
                asm volatile("s_waitcnt vmcnt(1)" ::: "memory");
            else
                asm volatile("s_waitcnt vmcnt(0)" ::: "memory");
        } else {
            asm volatile("s_waitcnt vmcnt(0)" ::: "memory");
        }
        __builtin_amdgcn_s_barrier();
        asm volatile("" ::: "memory");
        __builtin_amdgcn_sched_barrier(0);

        if (ki + 1 < 21) stage_B(ki + 1);
        if (ki + 3 < 21) stage_A(ki + 3);

        bf16x8 af[4];
#pragma unroll
        for (int rt = 0; rt < 4; ++rt)
            af[rt] = *(const bf16x8*)&As[ki & 3][(rt * 16 + m16) * 32 + koff];
        bf16x8 b0 = *(const bf16x8*)&Bs[ki & 1][(brb)*32 + koff];
        bf16x8 b1 = *(const bf16x8*)&Bs[ki & 1][(128 + brb) * 32 + koff];
        bf16x8 b2 = *(const bf16x8*)&Bs[ki & 1][(256 + brb) * 32 + koff];
#pragma unroll
        for (int rt = 0; rt < 4; ++rt)
            acc[rt][0] = __builtin_amdgcn_mfma_f32_16x16x32_bf16(af[rt], b0, acc[rt][0], 0, 0, 0);
#pragma unroll
        for (int rt = 0; rt < 4; ++rt)
            acc[rt][1] = __builtin_amdgcn_mfma_f32_16x16x32_bf16(af[rt], b1, acc[rt][1], 0, 0, 0);
        if (ki < 17) {
#pragma unroll
            for (int rt = 0; rt < 4; ++rt)
                acc[rt][2] = __builtin_amdgcn_mfma_f32_16x16x32_bf16(af[rt], b2, acc[rt][2], 0, 0, 0);
        } else {
#pragma unroll
            for (int rt = 0; rt < 4; ++rt)
                acc[rt][3] = __builtin_amdgcn_mfma_f32_16x16x32_bf16(af[rt], b2, acc[rt][3], 0, 0, 0);
        }
    }
    __syncthreads();  // all waves done reading Bs before it is reused as Ht

    short* Ht = &Bs[0][0];  // 64x128 bf16 = 16 KB
    {
        const int d = wave * 16 + m16;
        const float brs = bias512[d];
        const float bzs = bias512[128 + d];
        const float bin_ = bias512[256 + d];
        const float bhn = bias512[384 + d];
#pragma unroll
        for (int rt = 0; rt < 4; ++rt) {
#pragma unroll
            for (int j = 0; j < 4; ++j) {
                const int rowl = rt * 16 + quad * 4 + j;
                const int grow = row0 + rowl;
                const float rs = acc[rt][0][j] + brs;
                const float zs = acc[rt][1][j] + bzs;
                const float inn = acc[rt][2][j] + bin_;
                const float hnn = acc[rt][3][j] + bhn;
                const float rr = 1.0f / (1.0f + __expf(-rs));
                const float zz = 1.0f / (1.0f + __expf(-zs));
                const float ng = tanhf(inn + rr * hnn);
                const float hv =
                    bf2f(hbi[(size_t)(grow < NN ? grow : NN - 1) * DD + d]);
                const float o = (1.0f - zz) * ng + zz * hv;
                __hip_bfloat16 ob = __float2bfloat16(o);
                Ht[rowl * 128 + d] = *(short*)&ob;
            }
        }
    }
    __syncthreads();
    {
        const int row = tid >> 3;
        const int col = (tid & 7) * 16;
        if (row0 + row < NN) {
            bf16x8 v0 = *(const bf16x8*)&Ht[row * 128 + col];
            bf16x8 v1 = *(const bf16x8*)&Ht[row * 128 + col + 8];
            __hip_bfloat16* dstp = hbo + (size_t)(row0 + row) * DD + col;
            *(bf16x8*)dstp = v0;
            *(bf16x8*)(dstp + 8) = v1;
        }
    }
}

// ---------------------------------------------------------------- readout (n2g is sorted)
__global__ __launch_bounds__(128) void k_readout(const __hip_bfloat16* __restrict__ h,
                                                 const float* __restrict__ h1,
                                                 const int* __restrict__ n2g,
                                                 float* __restrict__ feats) {
    const int CHN = 64;
    int d = threadIdx.x;
    int v0 = blockIdx.x * CHN;
    if (v0 >= NN) return;
    int v1 = v0 + CHN;
    if (v1 > NN) v1 = NN;
    float sum = 0.0f;
    int cur = n2g[v0];
    for (int v = v0; v < v1; ++v) {
        int gph = n2g[v];
        if (gph != cur) {
            atomicAdd(&feats[cur * DD + d], sum);
            sum = 0.0f;
            cur = gph;
        }
        sum += bf2f(h[(size_t)v * DD + d]) + h1[(size_t)v * DD + d];
    }
    atomicAdd(&feats[cur * DD + d], sum);
}

// ---------------------------------------------------------------- classifier
__global__ void k_cls(const float* __restrict__ feats, const float* __restrict__ Wc,
                      const float* __restrict__ bc, float* __restrict__ out) {
    int t = threadIdx.x;
    if (t >= BB * 2) return;
    int b = t >> 1, c = t & 1;
    float s = bc[c];
    for (int d = 0; d < DD; ++d) s += feats[b * DD + d] * Wc[d * 2 + c];
    out[t] = s;
}

// ================================================================ launcher
extern "C" void kernel_launch(void* const* d_in, const int* in_sizes, int n_in, void* d_out,
                              int out_size, void* d_ws, size_t ws_size, hipStream_t stream) {
    const float* features = (const float*)d_in[0];
    const int* src = (const int*)d_in[1];
    const int* dst = (const int*)d_in[2];
    const int* etype = (const int*)d_in[3];
    const int* n2g = (const int*)d_in[4];
    const float* W_msg = (const float*)d_in[5];
    const float* b_msg = (const float*)d_in[6];
    const float* w_ih = (const float*)d_in[7];
    const float* b_ih = (const float*)d_in[8];
    const float* w_hh = (const float*)d_in[9];
    const float* b_hh = (const float*)d_in[10];
    const float* W_cls = (const float*)d_in[11];
    const float* b_cls = (const float*)d_in[12];
    float* out = (float*)d_out;

    char* ws = (char*)d_ws;
    size_t o = 0;
    auto alloc = [&](size_t bytes) {
        o = (o + 255) & ~(size_t)255;
        void* p = ws + o;
        o += bytes;
        return p;
    };
    int* deg2 = (int*)alloc(sizeof(int) * NBIN);
    int* off2 = (int*)alloc(sizeof(int) * (NBIN + 1));
    int* cursor = (int*)alloc(sizeof(int) * NBIN);
    int* bsum = (int*)alloc(sizeof(int) * NBLK);
    int* boff = (int*)alloc(sizeof(int) * NBLK);
    int* csr_src = (int*)alloc(sizeof(int) * EE);
    __hip_bfloat16* W2 = (__hip_bfloat16*)alloc(sizeof(__hip_bfloat16) * 512 * KTOT);
    float* bias512 = (float*)alloc(sizeof(float) * NGATES);
    float* hini = (float*)alloc(sizeof(float) * (size_t)NN * DD);
    __hip_bfloat16* hbfA = (__hip_bfloat16*)alloc(sizeof(__hip_bfloat16) * (size_t)NN * DD);
    __hip_bfloat16* hbfB = (__hip_bfloat16*)alloc(sizeof(__hip_bfloat16) * (size_t)NN * DD);
    __hip_bfloat16* g = (__hip_bfloat16*)alloc(sizeof(__hip_bfloat16) * (size_t)NN * KAGG);
    float* feats = (float*)alloc(sizeof(float) * BB * DD);

    // setup
    k_init_h<<<(NN * DD + 255) / 256, 256, 0, stream>>>(features, hini, hbfA);
    k_zero_i32<<<(NBIN + 255) / 256, 256, 0, stream>>>(deg2, NBIN);
    k_zero_f32<<<(BB * DD + 255) / 256, 256, 0, stream>>>(feats, BB * DD);
    k_hist<<<(EE + 255) / 256, 256, 0, stream>>>(dst, etype, deg2);
    k_scan_bsum<<<NBLK, 256, 0, stream>>>(deg2, bsum);
    k_scan_boff<<<1, 1024, 0, stream>>>(bsum, boff);
    k_scan_final<<<NBLK, 256, 0, stream>>>(deg2, boff, off2, cursor);
    k_fill<<<(EE + 255) / 256, 256, 0, stream>>>(dst, src, etype, cursor, csr_src);
    k_counts<<<(NN * 16 + 255) / 256, 256, 0, stream>>>(off2, g);
    {
        int prep_n = 512 * KTOT + NGATES;
        k_prep2<<<(prep_n + 255) / 256, 256, 0, stream>>>(W_msg, b_msg, w_ih, w_hh, b_ih,
                                                          b_hh, W2, bias512);
    }

    __hip_bfloat16* hbc = hbfA;
    __hip_bfloat16* hbx = hbfB;
    for (int s = 0; s < STEPS; ++s) {
        k_agg<<<(NN * 64 + 255) / 256, 256, 0, stream>>>(hbc, off2, csr_src, g);
        k_step<<<MT64, 512, 0, stream>>>(g, W2, bias512, hbc, hbx);
        __hip_bfloat16* tb = hbc; hbc = hbx; hbx = tb;
    }
    k_readout<<<(NN + 63) / 64, 128, 0, stream>>>(hbc, hini, n2g, feats);
    k_cls<<<1, 128, 0, stream>>>(feats, W_cls, b_cls, out);
}